// Round 10
// baseline (190.253 us; speedup 1.0000x reference)
//
#include <hip/hip_runtime.h>

// LSTM B=32768, T=50, I=2, H=32. 1024 blocks x 64 threads; ONE wave per block
// owns 32 batch rows as TWO independent M=16 row-groups (G0/G1).
// ILP-not-TLP: R7/R8/R9 all pinned at ~1.4 waves/SIMD, ~40% bubble. The two
// groups' MFMA chains + 16 activation sets interleave inside one wave, so a
// single resident wave fills its own bubbles. __launch_bounds__(64,1): 512
// VGPR budget -> no spill by construction (R5 lesson); grid = 1 wave/SIMD.
// Loop-invariants (Bh/Bl, head frags, wx/bias) are row-independent: SHARED.
// Core per group: full M=16 mfma_f32_16x16x32_bf16, split precision h
// (hh*Wh+hl*Wh+hh*Wl), h packed (lo16|hi16) u32 in private LDS, no barriers,
// head = 3 MFMAs vs replicated W_out, scales folded (-log2e/+2log2e),
// pair-batched rcp (pairs across groups), clamps on zg and c only.

#define TS 50
#define HSTR 36     // u32 stride of hpk rows (144 B): 16B-aligned
#define CL 14.0f    // exp2 arg clamp (zg, c)

typedef short short8 __attribute__((ext_vector_type(8)));
typedef float f32x4 __attribute__((ext_vector_type(4)));

__device__ __forceinline__ float fast_exp2(float x) {
    return __builtin_amdgcn_exp2f(x);
}
__device__ __forceinline__ float fast_rcp(float x) {
    return __builtin_amdgcn_rcpf(x);
}
// v ~= hi + lo (bf16 each, trunc). returns (lo<<16)|hi
__device__ __forceinline__ unsigned split_pack(float v) {
    unsigned u   = __float_as_uint(v);
    float    res = v - __uint_as_float(u & 0xffff0000u);
    return __builtin_amdgcn_perm(__float_as_uint(res), u, 0x07060302u);
}
// (a & 0xffff) | (b << 16)
__device__ __forceinline__ unsigned lo_pair(unsigned a, unsigned b) {
    return __builtin_amdgcn_perm(b, a, 0x05040100u);
}
// (a >> 16) | (b & 0xffff0000)
__device__ __forceinline__ unsigned hi_pair(unsigned a, unsigned b) {
    return __builtin_amdgcn_perm(b, a, 0x07060302u);
}

union U4S8 { uint4 v; short8 s; unsigned u[4]; };

__global__ __launch_bounds__(64, 1)
void lsnn_kernel(const float* __restrict__ x,
                 const float* __restrict__ W_ih,
                 const float* __restrict__ W_hh,
                 const float* __restrict__ b_ih,
                 const float* __restrict__ b_hh,
                 const float* __restrict__ W_out,
                 const float* __restrict__ b_out,
                 const float* __restrict__ h0,
                 const float* __restrict__ c0,
                 float* __restrict__ out)
{
    __shared__ __align__(16) float    x_lds[2][16 * 100];   // 12800 B
    __shared__ __align__(16) unsigned hpk[2][16 * HSTR];    //  4608 B
    __shared__ __align__(16) float    out_lds[2][16 * TS];  //  6400 B

    const int  lane = threadIdx.x;
    const int  u0   = lane & 15;
    const int  q    = lane >> 4;
    const long b0   = (long)blockIdx.x * 32;

    // ---- stage x: 3200 contiguous floats ([2][1600] matches row order) ----
    {
        const float4* xs = (const float4*)(x + b0 * 100);
        float4* xd = (float4*)&x_lds[0][0];
        for (int i = lane; i < 800; i += 64) xd[i] = xs[i];
    }
    // ---- init packed h0: 1024 values ----
    for (int i = lane; i < 1024; i += 64) {
        int g = i >> 9, r = (i >> 5) & 15, u = i & 31;
        hpk[g][r * HSTR + u] = split_pack(h0[b0 * 32 + i]);
    }

    const float L2E = 1.4426950408889634f;
    const float SG  = 2.0f * L2E;

    // ---- W_hh B-tiles (8): tile n -> gate n>>1, unit-half n&1, col u0.
    //      Row-independent: shared by both groups. ----
    short8 Bh[8], Bl[8];
    float  wx0[8], wx1[8], bias[8];
    #pragma unroll
    for (int n = 0; n < 8; ++n) {
        const float s = ((n >> 1) == 2) ? (2.0f * L2E) : -L2E;
        const int   gg = n * 16 + u0;
        const float* wr = W_hh + gg * 32 + q * 8;
        U4S8 uh, ul;
        #pragma unroll
        for (int p = 0; p < 4; ++p) {
            unsigned p0 = split_pack(wr[2*p]   * s);
            unsigned p1 = split_pack(wr[2*p+1] * s);
            uh.u[p] = lo_pair(p0, p1);
            ul.u[p] = hi_pair(p0, p1);
        }
        Bh[n] = uh.s;  Bl[n] = ul.s;
        wx0[n]  = W_ih[gg * 2 + 0] * s;
        wx1[n]  = W_ih[gg * 2 + 1] * s;
        bias[n] = (b_ih[gg] + b_hh[gg]) * s;
    }
    // ---- head B-frag: B[k][n] = w_out[k] replicated over n (shared) ----
    short8 Bwh, Bwl;
    {
        U4S8 uh, ul;
        #pragma unroll
        for (int p = 0; p < 4; ++p) {
            unsigned p0 = split_pack(W_out[q * 8 + 2*p]);
            unsigned p1 = split_pack(W_out[q * 8 + 2*p + 1]);
            uh.u[p] = lo_pair(p0, p1);
            ul.u[p] = hi_pair(p0, p1);
        }
        Bwh = uh.s;  Bwl = ul.s;
    }
    const float bout = b_out[0];

    // ---- c-state: [group][set], set = hu*4+r -> row q*4+r, unit hu*16+u0 ----
    float cst[2][8];
    #pragma unroll
    for (int g = 0; g < 2; ++g)
        #pragma unroll
        for (int hu = 0; hu < 2; ++hu)
            #pragma unroll
            for (int r = 0; r < 4; ++r)
                cst[g][hu * 4 + r] =
                    c0[(b0 + g * 16 + q * 4 + r) * 32 + hu * 16 + u0];

    const f32x4 ZV = {0.f, 0.f, 0.f, 0.f};
    const int abase = u0 * HSTR + q * 8;

    // ---- x prefetch for t=0 ----
    float2 xv[2][4];
    #pragma unroll
    for (int g = 0; g < 2; ++g)
        #pragma unroll
        for (int r = 0; r < 4; ++r)
            xv[g][r] = *(const float2*)&x_lds[g][(q * 4 + r) * 100];

    #pragma unroll 1
    for (int t = 0; t < TS; ++t) {
        // ---- A-fragments for both groups ----
        U4S8 Ahh[2], Ahl[2];
        #pragma unroll
        for (int g = 0; g < 2; ++g) {
            uint4 hq0 = *(const uint4*)&hpk[g][abase];
            uint4 hq1 = *(const uint4*)&hpk[g][abase + 4];
            Ahh[g].u[0] = lo_pair(hq0.x, hq0.y); Ahh[g].u[1] = lo_pair(hq0.z, hq0.w);
            Ahh[g].u[2] = lo_pair(hq1.x, hq1.y); Ahh[g].u[3] = lo_pair(hq1.z, hq1.w);
            Ahl[g].u[0] = hi_pair(hq0.x, hq0.y); Ahl[g].u[1] = hi_pair(hq0.z, hq0.w);
            Ahl[g].u[2] = hi_pair(hq1.x, hq1.y); Ahl[g].u[3] = hi_pair(hq1.z, hq1.w);
        }

        // ---- output head for h_t (both groups; skip t=0) ----
        if (t > 0) {
            #pragma unroll
            for (int g = 0; g < 2; ++g) {
                f32x4 aw = ZV;
                aw = __builtin_amdgcn_mfma_f32_16x16x32_bf16(Ahh[g].s, Bwh, aw, 0, 0, 0);
                aw = __builtin_amdgcn_mfma_f32_16x16x32_bf16(Ahl[g].s, Bwh, aw, 0, 0, 0);
                aw = __builtin_amdgcn_mfma_f32_16x16x32_bf16(Ahh[g].s, Bwl, aw, 0, 0, 0);
                if (u0 == 0) {
                    #pragma unroll
                    for (int r = 0; r < 4; ++r)
                        out_lds[g][(q * 4 + r) * TS + (t - 1)] = aw[r] + bout;
                }
            }
        }

        // ---- gates: 16 independent MFMA chains (8 tiles x 2 groups) ----
        f32x4 acc[2][8];
        #pragma unroll
        for (int n = 0; n < 8; ++n) {
            #pragma unroll
            for (int g = 0; g < 2; ++g) {
                f32x4 ci;
                #pragma unroll
                for (int r = 0; r < 4; ++r)
                    ci[r] = fmaf(wx1[n], xv[g][r].y,
                                 fmaf(wx0[n], xv[g][r].x, bias[n]));
                acc[g][n] = __builtin_amdgcn_mfma_f32_16x16x32_bf16(Ahh[g].s, Bh[n], ci,        0, 0, 0);
                acc[g][n] = __builtin_amdgcn_mfma_f32_16x16x32_bf16(Ahl[g].s, Bh[n], acc[g][n], 0, 0, 0);
                acc[g][n] = __builtin_amdgcn_mfma_f32_16x16x32_bf16(Ahh[g].s, Bl[n], acc[g][n], 0, 0, 0);
            }
        }

        // ---- prefetch x for t+1 ----
        if (t + 1 < TS) {
            #pragma unroll
            for (int g = 0; g < 2; ++g)
                #pragma unroll
                for (int r = 0; r < 4; ++r)
                    xv[g][r] = *(const float2*)
                        &x_lds[g][(q * 4 + r) * 100 + 2 * (t + 1)];
        }

        // ---- activations: 16 sets s = g*8 + hu*4 + r; pair rcp (s, s+8) ----
        float Bvs[16], Cvs[16], abps[16], epvs[16], pps[16];
        #pragma unroll
        for (int s = 0; s < 16; ++s) {
            const int g = s >> 3, hu = (s >> 2) & 1, r = s & 3;
            float zi = acc[g][0 + hu][r];               // i (scaled -log2e)
            float zf = acc[g][2 + hu][r];               // f (scaled -log2e)
            float zg = fminf(acc[g][4 + hu][r], CL);    // g (scaled +2log2e)
            float zo = acc[g][6 + hu][r];               // o (scaled -log2e)
            float Av = fast_exp2(zi);
            Bvs[s]   = fast_exp2(zg);
            float Ev = fast_exp2(zf);
            Cvs[s]   = fast_exp2(zo);
            float Ap = 1.0f + Av, Bp = 1.0f + Bvs[s];
            epvs[s]  = 1.0f + Ev;
            abps[s]  = Ap * Bp;
            pps[s]   = abps[s] * epvs[s];
        }
        float rgs[16];
        #pragma unroll
        for (int s = 0; s < 8; ++s) {
            float pr = pps[s] * pps[s + 8];
            float ri = fast_rcp(pr);
            rgs[s]     = pps[s + 8] * ri;
            rgs[s + 8] = pps[s]     * ri;
        }
        float Dvs[16], qvs[16];
        #pragma unroll
        for (int s = 0; s < 16; ++s) {
            const int g = s >> 3;
            float fv = abps[s] * rgs[s];                       // sigmoid(f)
            float ig = (Bvs[s] - 1.0f) * (epvs[s] * rgs[s]);   // sig(i)*tanh(g)
            float c  = fmaf(fv, cst[g][s & 7], ig);
            cst[g][s & 7] = c;
            Dvs[s] = fast_exp2(fminf(SG * c, CL));             // e^{2c}
            qvs[s] = (1.0f + Cvs[s]) * (1.0f + Dvs[s]);
        }
        float rqs[16];
        #pragma unroll
        for (int s = 0; s < 8; ++s) {
            float qr = qvs[s] * qvs[s + 8];
            float ri = fast_rcp(qr);
            rqs[s]     = qvs[s + 8] * ri;
            rqs[s + 8] = qvs[s]     * ri;
        }
        #pragma unroll
        for (int s = 0; s < 16; ++s) {
            const int g = s >> 3, hu = (s >> 2) & 1, r = s & 3;
            float h = (Dvs[s] - 1.0f) * rqs[s];                // sig(o)*tanh(c)
            hpk[g][(q * 4 + r) * HSTR + hu * 16 + u0] = split_pack(h);
        }
    }

    // ---- final head for h_50 (both groups) ----
    #pragma unroll
    for (int g = 0; g < 2; ++g) {
        uint4 hq0 = *(const uint4*)&hpk[g][abase];
        uint4 hq1 = *(const uint4*)&hpk[g][abase + 4];
        U4S8 Ahh, Ahl;
        Ahh.u[0] = lo_pair(hq0.x, hq0.y); Ahh.u[1] = lo_pair(hq0.z, hq0.w);
        Ahh.u[2] = lo_pair(hq1.x, hq1.y); Ahh.u[3] = lo_pair(hq1.z, hq1.w);
        Ahl.u[0] = hi_pair(hq0.x, hq0.y); Ahl.u[1] = hi_pair(hq0.z, hq0.w);
        Ahl.u[2] = hi_pair(hq1.x, hq1.y); Ahl.u[3] = hi_pair(hq1.z, hq1.w);
        f32x4 aw = {0.f, 0.f, 0.f, 0.f};
        aw = __builtin_amdgcn_mfma_f32_16x16x32_bf16(Ahh.s, Bwh, aw, 0, 0, 0);
        aw = __builtin_amdgcn_mfma_f32_16x16x32_bf16(Ahl.s, Bwh, aw, 0, 0, 0);
        aw = __builtin_amdgcn_mfma_f32_16x16x32_bf16(Ahh.s, Bwl, aw, 0, 0, 0);
        if (u0 == 0) {
            #pragma unroll
            for (int r = 0; r < 4; ++r)
                out_lds[g][(q * 4 + r) * TS + 49] = aw[r] + bout;
        }
    }

    // ---- coalesced flush: 1600 contiguous floats ----
    {
        float4* od = (float4*)(out + b0 * 50);
        const float4* os = (const float4*)&out_lds[0][0];
        for (int i = lane; i < 400; i += 64) od[i] = os[i];
    }
}

extern "C" void kernel_launch(void* const* d_in, const int* in_sizes, int n_in,
                              void* d_out, int out_size, void* d_ws, size_t ws_size,
                              hipStream_t stream) {
    const float* x     = (const float*)d_in[0];
    const float* W_ih  = (const float*)d_in[1];
    const float* W_hh  = (const float*)d_in[2];
    const float* b_ih  = (const float*)d_in[3];
    const float* b_hh  = (const float*)d_in[4];
    const float* W_out = (const float*)d_in[5];
    const float* b_out = (const float*)d_in[6];
    const float* h0    = (const float*)d_in[7];
    const float* c0    = (const float*)d_in[8];
    float* out = (float*)d_out;

    dim3 grid(32768 / 32), block(64);
    lsnn_kernel<<<grid, block, 0, stream>>>(x, W_ih, W_hh, b_ih, b_hh,
                                            W_out, b_out, h0, c0, out);
}